// Round 16
// baseline (217.586 us; speedup 1.0000x reference)
//
#include <hip/hip_runtime.h>
#include <hip/hip_fp16.h>
#include <cmath>

#define DIM_M 1024   // B (batch)
#define DIM_K 8192   // D
#define DIM_N 4096   // U
#define SPLIT 4
#define KSPL  (DIM_K / SPLIT)   // 2048
#define BKT   64
#define NT    (KSPL / BKT)      // 32 K-tiles per block
#define NB    1024              // scatter bins (4 u-rows = 128 KB fp32 region each)
#define EPB   8192              // entries per block in cluster
#define CVTB  1024              // cvt tail blocks fused into cluster grid

typedef __attribute__((ext_vector_type(8))) _Float16 half8;
typedef __attribute__((ext_vector_type(4))) float floatx4;

struct __align__(8) Half4 { __half2 a, b; };

__device__ inline void gload_lds16(const void* g, void* l) {
    __builtin_amdgcn_global_load_lds(
        (const __attribute__((address_space(1))) void*)g,
        (__attribute__((address_space(3))) void*)l, 16, 0, 0);
}

// ---------------------------------------------------------------------------
// Fused prep kernel. Blocks [0, nblk): one-pass cluster (local hist + scan +
// LDS scatter-by-bin + block-local contiguous writeout + per-block offsets).
// Blocks [nblk, nblk+CVTB): x fp32 -> fp16 convert (streaming BW overlap).
// ---------------------------------------------------------------------------
__global__ __launch_bounds__(512) void cluster_k(const int* __restrict__ ind,
                                                 const float* __restrict__ kv,
                                                 uint2* __restrict__ ebuf,
                                                 unsigned* __restrict__ ofs,  // [nblk][NB+1]
                                                 int nnz, int nblk,
                                                 const floatx4* __restrict__ xin,
                                                 Half4* __restrict__ xout) {
    extern __shared__ char csm[];
    const int tid = threadIdx.x;

    if (blockIdx.x >= nblk) {
        const int cb = blockIdx.x - nblk;
        const int base = cb * 2048;
        #pragma unroll
        for (int j = 0; j < 4; ++j) {
            int i = base + j * 512 + tid;
            floatx4 f = xin[i];
            Half4 h;
            h.a = __floats2half2_rn(f.x, f.y);
            h.b = __floats2half2_rn(f.z, f.w);
            xout[i] = h;
        }
        return;
    }

    uint2*    buf = (uint2*)csm;                  // 64 KB: entries clustered by bin
    unsigned* cur = (unsigned*)(csm + 65536);     //  4 KB: hist -> cursor
    unsigned* ss  = (unsigned*)(csm + 69632);     //  2 KB: 512 pair-sums for scan
    const int blk = blockIdx.x;
    const int base = blk * EPB;
    const int lim = min(nnz - base, EPB);
    const int4*   ip = (const int4*)(ind + 2 * (size_t)base);
    const float2* vp = (const float2*)(kv + base);

    for (int i = tid; i < NB; i += 512) cur[i] = 0u;
    __syncthreads();
    for (int k2 = tid; k2 < lim / 2; k2 += 512) {
        int4 w = ip[k2];
        atomicAdd(&cur[w.y >> 2], 1u);
        atomicAdd(&cur[w.w >> 2], 1u);
    }
    if ((lim & 1) && tid == 0) {
        int u = ind[2 * (size_t)(base + lim - 1) + 1];
        atomicAdd(&cur[u >> 2], 1u);
    }
    __syncthreads();
    unsigned c0 = cur[2 * tid], c1 = cur[2 * tid + 1];
    unsigned own = c0 + c1;
    ss[tid] = own;
    __syncthreads();
    for (int off = 1; off < 512; off <<= 1) {
        unsigned t = (tid >= off) ? ss[tid - off] : 0u;
        __syncthreads();
        ss[tid] += t;
        __syncthreads();
    }
    unsigned e0 = ss[tid] - own;
    unsigned e1 = e0 + c0;
    __syncthreads();
    cur[2 * tid]     = e0;
    cur[2 * tid + 1] = e1;
    unsigned* obase = ofs + (size_t)blk * (NB + 1);
    obase[2 * tid]     = e0;
    obase[2 * tid + 1] = e1;
    if (tid == 511) obase[NB] = ss[511];   // = lim
    __syncthreads();
    for (int k2 = tid; k2 < lim / 2; k2 += 512) {
        int4 w = ip[k2];
        float2 v = vp[k2];
        unsigned r0 = atomicAdd(&cur[w.y >> 2], 1u);
        buf[r0] = make_uint2(((unsigned)(w.y & 3) << 13) | (unsigned)w.x, __float_as_uint(v.x));
        unsigned r1 = atomicAdd(&cur[w.w >> 2], 1u);
        buf[r1] = make_uint2(((unsigned)(w.w & 3) << 13) | (unsigned)w.z, __float_as_uint(v.y));
    }
    if ((lim & 1) && tid == 0) {
        size_t e = (size_t)base + lim - 1;
        int d = ind[2 * e], u = ind[2 * e + 1];
        unsigned r = atomicAdd(&cur[u >> 2], 1u);
        buf[r] = make_uint2(((unsigned)(u & 3) << 13) | (unsigned)d, __float_as_uint(kv[e]));
    }
    __syncthreads();
    for (int j = tid; j < lim; j += 512)
        ebuf[(size_t)blk * EPB + j] = buf[j];
}

// ---------------------------------------------------------------------------
// Per-bin accumulate: 2 threads per block-segment (parity-split), ds_add into
// 128 KB fp32 LDS, dense fp16 writeout (replaces zero-fill too).
// ---------------------------------------------------------------------------
__global__ __launch_bounds__(512) void accum_k(const uint2* __restrict__ ebuf,
                                               const unsigned* __restrict__ ofs,
                                               int nblk,
                                               Half4* __restrict__ wh4) {
    extern __shared__ float reg[];            // 32768 floats = 128 KB
    floatx4* reg4 = (floatx4*)reg;
    const int tid = threadIdx.x, bin = blockIdx.x;
    for (int i = tid; i < 8192; i += 512) reg4[i] = floatx4{0.f, 0.f, 0.f, 0.f};
    __syncthreads();
    for (int s2 = tid; s2 < 2 * nblk; s2 += 512) {
        const int sb = s2 >> 1;
        const unsigned* ob = ofs + (size_t)sb * (NB + 1) + bin;
        unsigned o0 = ob[0] + (s2 & 1), o1 = ob[1];
        const uint2* p = ebuf + (size_t)sb * EPB;
        for (unsigned e = o0; e < o1; e += 2) {
            uint2 v = p[e];
            atomicAdd(&reg[v.x], __uint_as_float(v.y));   // ds_add_f32
        }
    }
    __syncthreads();
    for (int i = tid; i < 8192; i += 512) {
        floatx4 f = reg4[i];
        Half4 h;
        h.a = __floats2half2_rn(f.x, f.y);
        h.b = __floats2half2_rn(f.z, f.w);
        wh4[(size_t)bin * 8192 + i] = h;
    }
}

// ---------------------------------------------------------------------------
// GEMM: A DIRECT FROM GLOBAL via plain C++ prefetch loads (compiler-tracked —
// R14's inline-asm loads raced register allocation and failed refcheck).
// B-only LDS ring-3 (3 x 32KB). R7 geometry: 256x256 split-K tile, BKT=64,
// 1024 thr (16 waves of 64x64, acc[4][4]). Per K-tile: ONE raw barrier, then
// 2 phases {4 bF ds_read -> (ph0: stage tile t+2) -> prefetch next aF (plain
// loads) -> 16 MFMA on previously-prefetched aF}. Compiler emits the counted
// vmcnt/lgkm waits (by issue order it must leave {stage,nextA}=5 in flight).
// LDS reads halve vs R7 (128 ds_read_b128/K-tile); A rides the VMEM port
// (x is L2/L3-resident). Hazards: stage(t+2) overwrites buf(t-1) — reads of
// it completed before the tile barrier (each wave's lgkm wait precedes it);
// stage landing before read is covered by each wave's A-wait at iter t+1.
// Tail A/stage overruns land in adjacent ws regions (never consumed).
// ---------------------------------------------------------------------------
__global__ __launch_bounds__(1024, 4) void gemm8_k(
    const _Float16* __restrict__ Ah,   // [M][K] fp16
    const _Float16* __restrict__ Bh,   // [N][K] fp16
    _Float16*       __restrict__ part) // [SPLIT][M][N] fp16
{
    extern __shared__ char smem[];     // 3 x 32KB B ring buffers

    const int tid  = threadIdx.x;
    const int lane = tid & 63;
    const int wave = tid >> 6;           // 0..15

    const int bid = blockIdx.x;
    const int swz = (bid & 7) * 32 + (bid >> 3);
    const int n0  = (swz >> 4) * 256;
    const int rem = swz & 15;
    const int m0  = (rem >> 2) * 256;
    const int sp  = rem & 3;
    const size_t kbase = (size_t)sp * KSPL;

    // --- B staging: row = tid>>3 (0..127) (+128 for second gload), chunk tid&7
    const int srow = tid >> 3;
    const int sch  = (tid & 7) ^ (srow & 7);
    const _Float16* bSg = Bh + (size_t)(n0 + srow) * DIM_K + kbase + sch * 8;
    const int sofs = wave * 1024;

    // --- B read side (LDS, swizzled); wave tile 64x64
    const int wn  = wave & 3;            // N quadrant
    const int wrm = wave >> 2;           // M quadrant
    const int q   = lane >> 4;
    const int l7  = lane & 7;
    const int bRdOfs = (wn * 64 + (lane & 15)) * 128;
    const int ch0 = (q ^ l7) * 16;
    const int ch1 = ((4 + q) ^ l7) * 16;

    // --- A read side (global): row m0 + wrm*64 + i*16 + (lane&15), k = q*8 + 32*phase
    const half8* aP = (const half8*)(Ah + (size_t)(m0 + wrm * 64 + (lane & 15)) * DIM_K
                                     + kbase + q * 8);
    // i-th row-group offset: 16 rows * DIM_K / 8 = 16384 half8; phase advance: 4 half8

    floatx4 acc[4][4] = {};
    half8 aFA[4], aFB[4], bF[4];

#define STAGE2(SB)                                                            \
    { gload_lds16(bSg,                        (SB) + sofs);                   \
      gload_lds16(bSg + (size_t)128 * DIM_K,  (SB) + 16384 + sofs);           \
      bSg += BKT; }

#define LOADA(DST)                                                            \
    { _Pragma("unroll") for (int i = 0; i < 4; ++i)                           \
        DST[i] = aP[(size_t)i * 16384];                                       \
      aP += 4; }

#define RDB(CH)                                                               \
    { _Pragma("unroll") for (int i = 0; i < 4; ++i)                           \
        bF[i] = *(const half8*)(rb + bRdOfs + i * 2048 + (CH)); }

#define MM(AU)                                                                \
    __builtin_amdgcn_s_setprio(1);                                            \
    { _Pragma("unroll") for (int mi = 0; mi < 4; ++mi)                        \
        _Pragma("unroll") for (int ni = 0; ni < 4; ++ni)                      \
          acc[mi][ni] = __builtin_amdgcn_mfma_f32_16x16x32_f16(               \
              AU[mi], bF[ni], acc[mi][ni], 0, 0, 0); }                        \
    __builtin_amdgcn_s_setprio(0);

    // prologue: stage tiles 0,1 -> bufs 0,1; prefetch aF(t0,ph0).
    // vmcnt(2): stage builtins keep relative order, so the 2 newest VMEM ops
    // are never tile-0's stages -> tile 0 is landed under any legal reorder.
    char* rb = smem;
    char* sb = smem + 2 * 32768;
    STAGE2(smem)
    STAGE2(smem + 32768)
    LOADA(aFA)
    asm volatile("s_waitcnt vmcnt(2)" ::: "memory");
    __builtin_amdgcn_s_barrier();

    for (int t = 0; t < NT; ++t) {
        // phase 0: read bF(ch0), stage tile t+2, prefetch aF(t,ph1), MFMA aF(t,ph0)
        RDB(ch0)
        STAGE2(sb)
        LOADA(aFB)
        MM(aFA)
        // phase 1: read bF(ch1), prefetch aF(t+1,ph0), MFMA aF(t,ph1)
        RDB(ch1)
        LOADA(aFA)
        MM(aFB)
        rb = (rb == smem + 2 * 32768) ? smem : rb + 32768;
        sb = (sb == smem + 2 * 32768) ? smem : sb + 32768;
        __builtin_amdgcn_s_barrier();   // all waves done reading tile t's buffer
    }

#undef MM
#undef RDB
#undef LOADA
#undef STAGE2

    // epilogue: fp16 partials (C/D layout: col = lane&15, row = q*4 + r)
    _Float16* pbase = part + (size_t)sp * DIM_M * DIM_N;
    #pragma unroll
    for (int ni = 0; ni < 4; ++ni) {
        const int col = n0 + wn * 64 + ni * 16 + (lane & 15);
        #pragma unroll
        for (int mi = 0; mi < 4; ++mi) {
            const int row = m0 + wrm * 64 + mi * 16 + (q << 2);
            #pragma unroll
            for (int r = 0; r < 4; ++r)
                pbase[(size_t)(row + r) * DIM_N + col] = (_Float16)acc[mi][ni][r];
        }
    }
}

// out = tanh(sum_splits(fp16 part) + bias), 4 outputs/thread
__global__ void reduce_tanh(const Half4* __restrict__ part, const float* __restrict__ bias,
                            floatx4* __restrict__ out) {
    const int n4 = DIM_M * DIM_N / 4;
    int i = blockIdx.x * blockDim.x + threadIdx.x;
    if (i < n4) {
        float sx = 0.f, sy = 0.f, sz = 0.f, sw = 0.f;
        #pragma unroll
        for (int sp = 0; sp < SPLIT; ++sp) {
            Half4 p = part[(size_t)sp * n4 + i];
            float2 lo = __half22float2(p.a);
            float2 hi = __half22float2(p.b);
            sx += lo.x; sy += lo.y; sz += hi.x; sw += hi.y;
        }
        floatx4 b = ((const floatx4*)bias)[i & (DIM_N / 4 - 1)];
        floatx4 o;
        o.x = tanhf(sx + b.x);
        o.y = tanhf(sy + b.y);
        o.z = tanhf(sz + b.z);
        o.w = tanhf(sw + b.w);
        out[i] = o;
    }
}

extern "C" void kernel_launch(void* const* d_in, const int* in_sizes, int n_in,
                              void* d_out, int out_size, void* d_ws, size_t ws_size,
                              hipStream_t stream) {
    const float* x    = (const float*)d_in[0];
    const float* kv   = (const float*)d_in[1];
    const float* bias = (const float*)d_in[2];
    const int*   ind  = (const int*)d_in[3];
    float* out = (float*)d_out;
    const int nnz = in_sizes[1];

    char* ws = (char*)d_ws;
    _Float16* wh = (_Float16*)ws;                               // [N][K] fp16, 64 MB
    const size_t whBytes = (size_t)DIM_N * DIM_K * 2;
    _Float16* xh = (_Float16*)(ws + whBytes);                   // [M][K] fp16, 16 MB
    const size_t xhBytes = (size_t)DIM_M * DIM_K * 2;
    _Float16* part = (_Float16*)(ws + whBytes + xhBytes);       // [SPLIT][M][N] fp16, 32 MB
    const size_t partBytes = (size_t)SPLIT * DIM_M * DIM_N * 2;
    uint2* ebuf = (uint2*)(ws + whBytes + xhBytes + partBytes); // nblk*EPB*8 B (<=16 MB)
    const size_t ebufBytes = (size_t)16 << 20;
    unsigned* ofs = (unsigned*)(ws + whBytes + xhBytes + partBytes + ebufBytes); // [nblk][NB+1]

    const int oN4 = DIM_M * DIM_N / 4;
    const int nblk = (nnz + EPB - 1) / EPB;

    hipFuncSetAttribute((const void*)cluster_k,
                        hipFuncAttributeMaxDynamicSharedMemorySize, 71680);
    cluster_k<<<nblk + CVTB, 512, 71680, stream>>>(ind, kv, ebuf, ofs, nnz, nblk,
                                                   (const floatx4*)x, (Half4*)xh);

    hipFuncSetAttribute((const void*)accum_k,
                        hipFuncAttributeMaxDynamicSharedMemorySize, 131072);
    accum_k<<<NB, 512, 131072, stream>>>(ebuf, ofs, nblk, (Half4*)wh);

    hipFuncSetAttribute((const void*)gemm8_k,
                        hipFuncAttributeMaxDynamicSharedMemorySize, 98304);
    gemm8_k<<<dim3(256), 1024, 98304, stream>>>(xh, wh, part);

    reduce_tanh<<<(oN4 + 255) / 256, 256, 0, stream>>>((const Half4*)part, bias, (floatx4*)out);
}

// Round 17
// 115.861 us; speedup vs baseline: 1.8780x; 1.8780x over previous
//
#include <hip/hip_runtime.h>
#include <hip/hip_fp16.h>
#include <cmath>

#define DIM_M 1024   // B (batch)
#define DIM_K 8192   // D
#define DIM_N 4096   // U
#define SPLIT 4
#define KSPL  (DIM_K / SPLIT)   // 2048
#define BKT   64
#define NT    (KSPL / BKT)      // 32 K-tiles per block
#define NB    1024              // scatter bins (4 u-rows = 128 KB fp32 region each)
#define EPB   8192              // entries per block in cluster
#define CVTB  1024              // cvt tail blocks fused into cluster grid

typedef __attribute__((ext_vector_type(8))) _Float16 half8;
typedef __attribute__((ext_vector_type(4))) float floatx4;

struct __align__(8) Half4 { __half2 a, b; };

__device__ inline void gload_lds16(const void* g, void* l) {
    __builtin_amdgcn_global_load_lds(
        (const __attribute__((address_space(1))) void*)g,
        (__attribute__((address_space(3))) void*)l, 16, 0, 0);
}

// ---------------------------------------------------------------------------
// Fused prep kernel. Blocks [0, nblk): one-pass cluster (local hist + scan +
// LDS scatter-by-bin + block-local contiguous writeout + per-block offsets).
// Blocks [nblk, nblk+CVTB): x fp32 -> fp16 convert (streaming BW overlap).
// ---------------------------------------------------------------------------
__global__ __launch_bounds__(512) void cluster_k(const int* __restrict__ ind,
                                                 const float* __restrict__ kv,
                                                 uint2* __restrict__ ebuf,
                                                 unsigned* __restrict__ ofs,  // [nblk][NB+1]
                                                 int nnz, int nblk,
                                                 const floatx4* __restrict__ xin,
                                                 Half4* __restrict__ xout) {
    extern __shared__ char csm[];
    const int tid = threadIdx.x;

    if (blockIdx.x >= nblk) {
        const int cb = blockIdx.x - nblk;
        const int base = cb * 2048;
        #pragma unroll
        for (int j = 0; j < 4; ++j) {
            int i = base + j * 512 + tid;
            floatx4 f = xin[i];
            Half4 h;
            h.a = __floats2half2_rn(f.x, f.y);
            h.b = __floats2half2_rn(f.z, f.w);
            xout[i] = h;
        }
        return;
    }

    uint2*    buf = (uint2*)csm;                  // 64 KB: entries clustered by bin
    unsigned* cur = (unsigned*)(csm + 65536);     //  4 KB: hist -> cursor
    unsigned* ss  = (unsigned*)(csm + 69632);     //  2 KB: 512 pair-sums for scan
    const int blk = blockIdx.x;
    const int base = blk * EPB;
    const int lim = min(nnz - base, EPB);
    const int4*   ip = (const int4*)(ind + 2 * (size_t)base);
    const float2* vp = (const float2*)(kv + base);

    for (int i = tid; i < NB; i += 512) cur[i] = 0u;
    __syncthreads();
    for (int k2 = tid; k2 < lim / 2; k2 += 512) {
        int4 w = ip[k2];
        atomicAdd(&cur[w.y >> 2], 1u);
        atomicAdd(&cur[w.w >> 2], 1u);
    }
    if ((lim & 1) && tid == 0) {
        int u = ind[2 * (size_t)(base + lim - 1) + 1];
        atomicAdd(&cur[u >> 2], 1u);
    }
    __syncthreads();
    unsigned c0 = cur[2 * tid], c1 = cur[2 * tid + 1];
    unsigned own = c0 + c1;
    ss[tid] = own;
    __syncthreads();
    for (int off = 1; off < 512; off <<= 1) {
        unsigned t = (tid >= off) ? ss[tid - off] : 0u;
        __syncthreads();
        ss[tid] += t;
        __syncthreads();
    }
    unsigned e0 = ss[tid] - own;
    unsigned e1 = e0 + c0;
    __syncthreads();
    cur[2 * tid]     = e0;
    cur[2 * tid + 1] = e1;
    unsigned* obase = ofs + (size_t)blk * (NB + 1);
    obase[2 * tid]     = e0;
    obase[2 * tid + 1] = e1;
    if (tid == 511) obase[NB] = ss[511];   // = lim
    __syncthreads();
    for (int k2 = tid; k2 < lim / 2; k2 += 512) {
        int4 w = ip[k2];
        float2 v = vp[k2];
        unsigned r0 = atomicAdd(&cur[w.y >> 2], 1u);
        buf[r0] = make_uint2(((unsigned)(w.y & 3) << 13) | (unsigned)w.x, __float_as_uint(v.x));
        unsigned r1 = atomicAdd(&cur[w.w >> 2], 1u);
        buf[r1] = make_uint2(((unsigned)(w.w & 3) << 13) | (unsigned)w.z, __float_as_uint(v.y));
    }
    if ((lim & 1) && tid == 0) {
        size_t e = (size_t)base + lim - 1;
        int d = ind[2 * e], u = ind[2 * e + 1];
        unsigned r = atomicAdd(&cur[u >> 2], 1u);
        buf[r] = make_uint2(((unsigned)(u & 3) << 13) | (unsigned)d, __float_as_uint(kv[e]));
    }
    __syncthreads();
    for (int j = tid; j < lim; j += 512)
        ebuf[(size_t)blk * EPB + j] = buf[j];
}

// ---------------------------------------------------------------------------
// Per-bin accumulate: 2 threads per block-segment (parity-split), ds_add into
// 128 KB fp32 LDS, dense fp16 writeout (replaces zero-fill too).
// ---------------------------------------------------------------------------
__global__ __launch_bounds__(512) void accum_k(const uint2* __restrict__ ebuf,
                                               const unsigned* __restrict__ ofs,
                                               int nblk,
                                               Half4* __restrict__ wh4) {
    extern __shared__ float reg[];            // 32768 floats = 128 KB
    floatx4* reg4 = (floatx4*)reg;
    const int tid = threadIdx.x, bin = blockIdx.x;
    for (int i = tid; i < 8192; i += 512) reg4[i] = floatx4{0.f, 0.f, 0.f, 0.f};
    __syncthreads();
    for (int s2 = tid; s2 < 2 * nblk; s2 += 512) {
        const int sb = s2 >> 1;
        const unsigned* ob = ofs + (size_t)sb * (NB + 1) + bin;
        unsigned o0 = ob[0] + (s2 & 1), o1 = ob[1];
        const uint2* p = ebuf + (size_t)sb * EPB;
        for (unsigned e = o0; e < o1; e += 2) {
            uint2 v = p[e];
            atomicAdd(&reg[v.x], __uint_as_float(v.y));   // ds_add_f32
        }
    }
    __syncthreads();
    for (int i = tid; i < 8192; i += 512) {
        floatx4 f = reg4[i];
        Half4 h;
        h.a = __floats2half2_rn(f.x, f.y);
        h.b = __floats2half2_rn(f.z, f.w);
        wh4[(size_t)bin * 8192 + i] = h;
    }
}

// ---------------------------------------------------------------------------
// GEMM: measured-best config (R7/R13): 256x256 split-K tile, BKT=64, 1024 thr
// (16 waves of 64x64 -> acc[4][4]=64 VGPR -> 4 waves/SIMD), ring-2 LDS
// 2x64KB, per K-tile 2 phases {8 ds_read -> lgkm(0) -> 16 MFMA}, 1 barrier-
// pair + batched STAGE + counted vmcnt(4). Raw s_barrier only. fp16 partials.
// (R5/R6/R8/R9/R10/R11 schedule variants and R14/R15 A-direct all <= this;
// the per-CU LDS-port + MFMA sum-law holds across 8 variants.)
// ---------------------------------------------------------------------------
__global__ __launch_bounds__(1024, 4) void gemm8_k(
    const _Float16* __restrict__ Ah,   // [M][K] fp16
    const _Float16* __restrict__ Bh,   // [N][K] fp16
    _Float16*       __restrict__ part) // [SPLIT][M][N] fp16
{
    extern __shared__ char smem[];

    const int tid  = threadIdx.x;
    const int lane = tid & 63;
    const int wave = tid >> 6;           // 0..15

    const int bid = blockIdx.x;
    const int swz = (bid & 7) * 32 + (bid >> 3);
    const int n0  = (swz >> 4) * 256;
    const int rem = swz & 15;
    const int m0  = (rem >> 2) * 256;
    const int sp  = rem & 3;
    const size_t kbase = (size_t)sp * KSPL;

    const int srow = tid >> 3;                   // 0..127
    const int sch  = (tid & 7) ^ (srow & 7);
    const _Float16* aSg = Ah + (size_t)(m0 + srow) * DIM_K + kbase + sch * 8;
    const _Float16* bSg = Bh + (size_t)(n0 + srow) * DIM_K + kbase + sch * 8;
    char* aLg = smem + wave * 1024;              // + C*65536 + p*16384
    char* bLg = smem + 32768 + wave * 1024;

    const int wn  = wave & 3;            // N quadrant
    const int wrm = wave >> 2;           // M quadrant
    const int q   = lane >> 4;
    const int l7  = lane & 7;
    const char* aRd = smem + (wrm * 64 + (lane & 15)) * 128;
    const char* bRd = smem + 32768 + (wn * 64 + (lane & 15)) * 128;
    const int ch0 = ((0 * 4 + q) ^ l7) * 16;
    const int ch1 = ((1 * 4 + q) ^ l7) * 16;

    floatx4 acc[4][4] = {};
    half8 aF[4], bF[4];

#define STAGE(C)                                                              \
    { _Pragma("unroll") for (int p = 0; p < 2; ++p) {                         \
        gload_lds16(aSg + (size_t)p * (128 * DIM_K), aLg + (C) * 65536 + p * 16384); \
        gload_lds16(bSg + (size_t)p * (128 * DIM_K), bLg + (C) * 65536 + p * 16384); } \
      aSg += BKT; bSg += BKT; }

#define PH(C, CH)                                                             \
    { _Pragma("unroll") for (int i = 0; i < 4; ++i)                           \
        aF[i] = *(const half8*)(aRd + (C) * 65536 + i * 2048 + (CH));         \
      _Pragma("unroll") for (int i = 0; i < 4; ++i)                           \
        bF[i] = *(const half8*)(bRd + (C) * 65536 + i * 2048 + (CH));         \
      asm volatile("s_waitcnt lgkmcnt(0)" ::: "memory");                      \
      __builtin_amdgcn_sched_barrier(0);                                      \
      __builtin_amdgcn_s_setprio(1);                                          \
      _Pragma("unroll") for (int mi = 0; mi < 4; ++mi)                        \
        _Pragma("unroll") for (int ni = 0; ni < 4; ++ni)                      \
          acc[mi][ni] = __builtin_amdgcn_mfma_f32_16x16x32_f16(               \
              aF[mi], bF[ni], acc[mi][ni], 0, 0, 0);                          \
      __builtin_amdgcn_s_setprio(0); }

#define KTILE(C) PH(C, ch0) PH(C, ch1)

    STAGE(0)
    STAGE(1)
    asm volatile("s_waitcnt vmcnt(4)" ::: "memory");
    __builtin_amdgcn_s_barrier();

    for (int t2 = 0; t2 < NT / 2; ++t2) {
        KTILE(0)
        __builtin_amdgcn_s_barrier();
        if (t2 < NT / 2 - 1) {
            STAGE(0)
            asm volatile("s_waitcnt vmcnt(4)" ::: "memory");
        } else {
            asm volatile("s_waitcnt vmcnt(0)" ::: "memory");
        }
        __builtin_amdgcn_s_barrier();
        KTILE(1)
        if (t2 < NT / 2 - 1) {
            __builtin_amdgcn_s_barrier();
            STAGE(1)
            asm volatile("s_waitcnt vmcnt(4)" ::: "memory");
            __builtin_amdgcn_s_barrier();
        }
    }

#undef KTILE
#undef PH
#undef STAGE

    // epilogue: fp16 partials (C/D layout: col = lane&15, row = q*4 + r)
    _Float16* pbase = part + (size_t)sp * DIM_M * DIM_N;
    #pragma unroll
    for (int ni = 0; ni < 4; ++ni) {
        const int col = n0 + wn * 64 + ni * 16 + (lane & 15);
        #pragma unroll
        for (int mi = 0; mi < 4; ++mi) {
            const int row = m0 + wrm * 64 + mi * 16 + (q << 2);
            #pragma unroll
            for (int r = 0; r < 4; ++r)
                pbase[(size_t)(row + r) * DIM_N + col] = (_Float16)acc[mi][ni][r];
        }
    }
}

// out = tanh(sum_splits(fp16 part) + bias), 4 outputs/thread
__global__ void reduce_tanh(const Half4* __restrict__ part, const float* __restrict__ bias,
                            floatx4* __restrict__ out) {
    const int n4 = DIM_M * DIM_N / 4;
    int i = blockIdx.x * blockDim.x + threadIdx.x;
    if (i < n4) {
        float sx = 0.f, sy = 0.f, sz = 0.f, sw = 0.f;
        #pragma unroll
        for (int sp = 0; sp < SPLIT; ++sp) {
            Half4 p = part[(size_t)sp * n4 + i];
            float2 lo = __half22float2(p.a);
            float2 hi = __half22float2(p.b);
            sx += lo.x; sy += lo.y; sz += hi.x; sw += hi.y;
        }
        floatx4 b = ((const floatx4*)bias)[i & (DIM_N / 4 - 1)];
        floatx4 o;
        o.x = tanhf(sx + b.x);
        o.y = tanhf(sy + b.y);
        o.z = tanhf(sz + b.z);
        o.w = tanhf(sw + b.w);
        out[i] = o;
    }
}

extern "C" void kernel_launch(void* const* d_in, const int* in_sizes, int n_in,
                              void* d_out, int out_size, void* d_ws, size_t ws_size,
                              hipStream_t stream) {
    const float* x    = (const float*)d_in[0];
    const float* kv   = (const float*)d_in[1];
    const float* bias = (const float*)d_in[2];
    const int*   ind  = (const int*)d_in[3];
    float* out = (float*)d_out;
    const int nnz = in_sizes[1];

    char* ws = (char*)d_ws;
    _Float16* wh = (_Float16*)ws;                               // [N][K] fp16, 64 MB
    const size_t whBytes = (size_t)DIM_N * DIM_K * 2;
    _Float16* xh = (_Float16*)(ws + whBytes);                   // [M][K] fp16, 16 MB
    const size_t xhBytes = (size_t)DIM_M * DIM_K * 2;
    _Float16* part = (_Float16*)(ws + whBytes + xhBytes);       // [SPLIT][M][N] fp16, 32 MB
    const size_t partBytes = (size_t)SPLIT * DIM_M * DIM_N * 2;
    uint2* ebuf = (uint2*)(ws + whBytes + xhBytes + partBytes); // nblk*EPB*8 B (<=16 MB)
    const size_t ebufBytes = (size_t)16 << 20;
    unsigned* ofs = (unsigned*)(ws + whBytes + xhBytes + partBytes + ebufBytes); // [nblk][NB+1]

    const int oN4 = DIM_M * DIM_N / 4;
    const int nblk = (nnz + EPB - 1) / EPB;

    hipFuncSetAttribute((const void*)cluster_k,
                        hipFuncAttributeMaxDynamicSharedMemorySize, 71680);
    cluster_k<<<nblk + CVTB, 512, 71680, stream>>>(ind, kv, ebuf, ofs, nnz, nblk,
                                                   (const floatx4*)x, (Half4*)xh);

    hipFuncSetAttribute((const void*)accum_k,
                        hipFuncAttributeMaxDynamicSharedMemorySize, 131072);
    accum_k<<<NB, 512, 131072, stream>>>(ebuf, ofs, nblk, (Half4*)wh);

    hipFuncSetAttribute((const void*)gemm8_k,
                        hipFuncAttributeMaxDynamicSharedMemorySize, 131072);
    gemm8_k<<<dim3(256), 1024, 131072, stream>>>(xh, wh, part);

    reduce_tanh<<<(oN4 + 255) / 256, 256, 0, stream>>>((const Half4*)part, bias, (floatx4*)out);
}

// Round 18
// 115.095 us; speedup vs baseline: 1.8905x; 1.0067x over previous
//
#include <hip/hip_runtime.h>
#include <hip/hip_fp16.h>
#include <cmath>

#define DIM_M 1024   // B (batch)
#define DIM_K 8192   // D
#define DIM_N 4096   // U
#define SPLIT 4
#define KSPL  (DIM_K / SPLIT)   // 2048
#define BKT   64
#define NT    (KSPL / BKT)      // 32 K-tiles per block
#define NB    1024              // scatter bins (4 u-rows = 128 KB fp32 region each)
#define EPB   8192              // entries per block in cluster
#define CVTB  1024              // cvt tail blocks fused into cluster grid

typedef __attribute__((ext_vector_type(8))) _Float16 half8;
typedef __attribute__((ext_vector_type(4))) float floatx4;

struct __align__(8) Half4 { __half2 a, b; };

__device__ inline void gload_lds16(const void* g, void* l) {
    __builtin_amdgcn_global_load_lds(
        (const __attribute__((address_space(1))) void*)g,
        (__attribute__((address_space(3))) void*)l, 16, 0, 0);
}

// ---------------------------------------------------------------------------
// Fused prep kernel. Blocks [0, nblk): one-pass cluster (local hist + scan +
// LDS scatter-by-bin + block-local contiguous writeout + per-block offsets).
// Blocks [nblk, nblk+CVTB): x fp32 -> fp16 convert (streaming BW overlap).
// ofs is written TRANSPOSED: ofs[bin * nblk + blk] (and row NB = totals) so
// accum_k's per-bin offset reads are coalesced rows.
// ---------------------------------------------------------------------------
__global__ __launch_bounds__(512) void cluster_k(const int* __restrict__ ind,
                                                 const float* __restrict__ kv,
                                                 uint2* __restrict__ ebuf,
                                                 unsigned* __restrict__ ofs,  // [NB+1][nblk]
                                                 int nnz, int nblk,
                                                 const floatx4* __restrict__ xin,
                                                 Half4* __restrict__ xout) {
    extern __shared__ char csm[];
    const int tid = threadIdx.x;

    if (blockIdx.x >= nblk) {
        const int cb = blockIdx.x - nblk;
        const int base = cb * 2048;
        #pragma unroll
        for (int j = 0; j < 4; ++j) {
            int i = base + j * 512 + tid;
            floatx4 f = xin[i];
            Half4 h;
            h.a = __floats2half2_rn(f.x, f.y);
            h.b = __floats2half2_rn(f.z, f.w);
            xout[i] = h;
        }
        return;
    }

    uint2*    buf = (uint2*)csm;                  // 64 KB: entries clustered by bin
    unsigned* cur = (unsigned*)(csm + 65536);     //  4 KB: hist -> cursor
    unsigned* ss  = (unsigned*)(csm + 69632);     //  2 KB: 512 pair-sums for scan
    const int blk = blockIdx.x;
    const int base = blk * EPB;
    const int lim = min(nnz - base, EPB);
    const int4*   ip = (const int4*)(ind + 2 * (size_t)base);
    const float2* vp = (const float2*)(kv + base);

    for (int i = tid; i < NB; i += 512) cur[i] = 0u;
    __syncthreads();
    for (int k2 = tid; k2 < lim / 2; k2 += 512) {
        int4 w = ip[k2];
        atomicAdd(&cur[w.y >> 2], 1u);
        atomicAdd(&cur[w.w >> 2], 1u);
    }
    if ((lim & 1) && tid == 0) {
        int u = ind[2 * (size_t)(base + lim - 1) + 1];
        atomicAdd(&cur[u >> 2], 1u);
    }
    __syncthreads();
    unsigned c0 = cur[2 * tid], c1 = cur[2 * tid + 1];
    unsigned own = c0 + c1;
    ss[tid] = own;
    __syncthreads();
    for (int off = 1; off < 512; off <<= 1) {
        unsigned t = (tid >= off) ? ss[tid - off] : 0u;
        __syncthreads();
        ss[tid] += t;
        __syncthreads();
    }
    unsigned e0 = ss[tid] - own;
    unsigned e1 = e0 + c0;
    __syncthreads();
    cur[2 * tid]     = e0;
    cur[2 * tid + 1] = e1;
    // transposed offsets: ofs[bin][blk]
    ofs[(size_t)(2 * tid)     * nblk + blk] = e0;
    ofs[(size_t)(2 * tid + 1) * nblk + blk] = e1;
    if (tid == 511) ofs[(size_t)NB * nblk + blk] = ss[511];   // = lim
    __syncthreads();
    for (int k2 = tid; k2 < lim / 2; k2 += 512) {
        int4 w = ip[k2];
        float2 v = vp[k2];
        unsigned r0 = atomicAdd(&cur[w.y >> 2], 1u);
        buf[r0] = make_uint2(((unsigned)(w.y & 3) << 13) | (unsigned)w.x, __float_as_uint(v.x));
        unsigned r1 = atomicAdd(&cur[w.w >> 2], 1u);
        buf[r1] = make_uint2(((unsigned)(w.w & 3) << 13) | (unsigned)w.z, __float_as_uint(v.y));
    }
    if ((lim & 1) && tid == 0) {
        size_t e = (size_t)base + lim - 1;
        int d = ind[2 * e], u = ind[2 * e + 1];
        unsigned r = atomicAdd(&cur[u >> 2], 1u);
        buf[r] = make_uint2(((unsigned)(u & 3) << 13) | (unsigned)d, __float_as_uint(kv[e]));
    }
    __syncthreads();
    for (int j = tid; j < lim; j += 512)
        ebuf[(size_t)blk * EPB + j] = buf[j];
}

// ---------------------------------------------------------------------------
// Per-bin accumulate: 1024 threads, 4 threads per block-segment (832 walkers
// in one pass, ~2-deep serial chains vs 4-deep before), coalesced transposed
// offset reads, ds_add into 128 KB fp32 LDS, dense fp16 writeout.
// ---------------------------------------------------------------------------
__global__ __launch_bounds__(1024) void accum_k(const uint2* __restrict__ ebuf,
                                                const unsigned* __restrict__ ofs,
                                                int nblk,
                                                Half4* __restrict__ wh4) {
    extern __shared__ float reg[];            // 32768 floats = 128 KB
    floatx4* reg4 = (floatx4*)reg;
    const int tid = threadIdx.x, bin = blockIdx.x;
    for (int i = tid; i < 8192; i += 1024) reg4[i] = floatx4{0.f, 0.f, 0.f, 0.f};
    __syncthreads();
    const unsigned* row0 = ofs + (size_t)bin * nblk;        // this bin's starts
    const unsigned* row1 = row0 + nblk;                     // next bin's starts
    for (int s4 = tid; s4 < 4 * nblk; s4 += 1024) {
        const int sb = s4 >> 2;
        unsigned o0 = row0[sb] + (s4 & 3), o1 = row1[sb];
        const uint2* p = ebuf + (size_t)sb * EPB;
        for (unsigned e = o0; e < o1; e += 4) {
            uint2 v = p[e];
            atomicAdd(&reg[v.x], __uint_as_float(v.y));   // ds_add_f32
        }
    }
    __syncthreads();
    for (int i = tid; i < 8192; i += 1024) {
        floatx4 f = reg4[i];
        Half4 h;
        h.a = __floats2half2_rn(f.x, f.y);
        h.b = __floats2half2_rn(f.z, f.w);
        wh4[(size_t)bin * 8192 + i] = h;
    }
}

// ---------------------------------------------------------------------------
// GEMM: measured-best config (R7/R13): 256x256 split-K tile, BKT=64, 1024 thr
// (16 waves of 64x64 -> acc[4][4]=64 VGPR -> 4 waves/SIMD), ring-2 LDS
// 2x64KB, per K-tile 2 phases {8 ds_read -> lgkm(0) -> 16 MFMA}, 1 barrier-
// pair + batched STAGE + counted vmcnt(4). Raw s_barrier only. fp16 partials.
// Frozen: 8 schedule/geometry variants all <= this (sum-law + VGPR math).
// ---------------------------------------------------------------------------
__global__ __launch_bounds__(1024, 4) void gemm8_k(
    const _Float16* __restrict__ Ah,   // [M][K] fp16
    const _Float16* __restrict__ Bh,   // [N][K] fp16
    _Float16*       __restrict__ part) // [SPLIT][M][N] fp16
{
    extern __shared__ char smem[];

    const int tid  = threadIdx.x;
    const int lane = tid & 63;
    const int wave = tid >> 6;           // 0..15

    const int bid = blockIdx.x;
    const int swz = (bid & 7) * 32 + (bid >> 3);
    const int n0  = (swz >> 4) * 256;
    const int rem = swz & 15;
    const int m0  = (rem >> 2) * 256;
    const int sp  = rem & 3;
    const size_t kbase = (size_t)sp * KSPL;

    const int srow = tid >> 3;                   // 0..127
    const int sch  = (tid & 7) ^ (srow & 7);
    const _Float16* aSg = Ah + (size_t)(m0 + srow) * DIM_K + kbase + sch * 8;
    const _Float16* bSg = Bh + (size_t)(n0 + srow) * DIM_K + kbase + sch * 8;
    char* aLg = smem + wave * 1024;              // + C*65536 + p*16384
    char* bLg = smem + 32768 + wave * 1024;

    const int wn  = wave & 3;            // N quadrant
    const int wrm = wave >> 2;           // M quadrant
    const int q   = lane >> 4;
    const int l7  = lane & 7;
    const char* aRd = smem + (wrm * 64 + (lane & 15)) * 128;
    const char* bRd = smem + 32768 + (wn * 64 + (lane & 15)) * 128;
    const int ch0 = ((0 * 4 + q) ^ l7) * 16;
    const int ch1 = ((1 * 4 + q) ^ l7) * 16;

    floatx4 acc[4][4] = {};
    half8 aF[4], bF[4];

#define STAGE(C)                                                              \
    { _Pragma("unroll") for (int p = 0; p < 2; ++p) {                         \
        gload_lds16(aSg + (size_t)p * (128 * DIM_K), aLg + (C) * 65536 + p * 16384); \
        gload_lds16(bSg + (size_t)p * (128 * DIM_K), bLg + (C) * 65536 + p * 16384); } \
      aSg += BKT; bSg += BKT; }

#define PH(C, CH)                                                             \
    { _Pragma("unroll") for (int i = 0; i < 4; ++i)                           \
        aF[i] = *(const half8*)(aRd + (C) * 65536 + i * 2048 + (CH));         \
      _Pragma("unroll") for (int i = 0; i < 4; ++i)                           \
        bF[i] = *(const half8*)(bRd + (C) * 65536 + i * 2048 + (CH));         \
      asm volatile("s_waitcnt lgkmcnt(0)" ::: "memory");                      \
      __builtin_amdgcn_sched_barrier(0);                                      \
      __builtin_amdgcn_s_setprio(1);                                          \
      _Pragma("unroll") for (int mi = 0; mi < 4; ++mi)                        \
        _Pragma("unroll") for (int ni = 0; ni < 4; ++ni)                      \
          acc[mi][ni] = __builtin_amdgcn_mfma_f32_16x16x32_f16(               \
              aF[mi], bF[ni], acc[mi][ni], 0, 0, 0);                          \
      __builtin_amdgcn_s_setprio(0); }

#define KTILE(C) PH(C, ch0) PH(C, ch1)

    STAGE(0)
    STAGE(1)
    asm volatile("s_waitcnt vmcnt(4)" ::: "memory");
    __builtin_amdgcn_s_barrier();

    for (int t2 = 0; t2 < NT / 2; ++t2) {
        KTILE(0)
        __builtin_amdgcn_s_barrier();
        if (t2 < NT / 2 - 1) {
            STAGE(0)
            asm volatile("s_waitcnt vmcnt(4)" ::: "memory");
        } else {
            asm volatile("s_waitcnt vmcnt(0)" ::: "memory");
        }
        __builtin_amdgcn_s_barrier();
        KTILE(1)
        if (t2 < NT / 2 - 1) {
            __builtin_amdgcn_s_barrier();
            STAGE(1)
            asm volatile("s_waitcnt vmcnt(4)" ::: "memory");
            __builtin_amdgcn_s_barrier();
        }
    }

#undef KTILE
#undef PH
#undef STAGE

    // epilogue: fp16 partials (C/D layout: col = lane&15, row = q*4 + r)
    _Float16* pbase = part + (size_t)sp * DIM_M * DIM_N;
    #pragma unroll
    for (int ni = 0; ni < 4; ++ni) {
        const int col = n0 + wn * 64 + ni * 16 + (lane & 15);
        #pragma unroll
        for (int mi = 0; mi < 4; ++mi) {
            const int row = m0 + wrm * 64 + mi * 16 + (q << 2);
            #pragma unroll
            for (int r = 0; r < 4; ++r)
                pbase[(size_t)(row + r) * DIM_N + col] = (_Float16)acc[mi][ni][r];
        }
    }
}

// out = tanh(sum_splits(fp16 part) + bias), 4 outputs/thread
__global__ void reduce_tanh(const Half4* __restrict__ part, const float* __restrict__ bias,
                            floatx4* __restrict__ out) {
    const int n4 = DIM_M * DIM_N / 4;
    int i = blockIdx.x * blockDim.x + threadIdx.x;
    if (i < n4) {
        float sx = 0.f, sy = 0.f, sz = 0.f, sw = 0.f;
        #pragma unroll
        for (int sp = 0; sp < SPLIT; ++sp) {
            Half4 p = part[(size_t)sp * n4 + i];
            float2 lo = __half22float2(p.a);
            float2 hi = __half22float2(p.b);
            sx += lo.x; sy += lo.y; sz += hi.x; sw += hi.y;
        }
        floatx4 b = ((const floatx4*)bias)[i & (DIM_N / 4 - 1)];
        floatx4 o;
        o.x = tanhf(sx + b.x);
        o.y = tanhf(sy + b.y);
        o.z = tanhf(sz + b.z);
        o.w = tanhf(sw + b.w);
        out[i] = o;
    }
}

extern "C" void kernel_launch(void* const* d_in, const int* in_sizes, int n_in,
                              void* d_out, int out_size, void* d_ws, size_t ws_size,
                              hipStream_t stream) {
    const float* x    = (const float*)d_in[0];
    const float* kv   = (const float*)d_in[1];
    const float* bias = (const float*)d_in[2];
    const int*   ind  = (const int*)d_in[3];
    float* out = (float*)d_out;
    const int nnz = in_sizes[1];

    char* ws = (char*)d_ws;
    _Float16* wh = (_Float16*)ws;                               // [N][K] fp16, 64 MB
    const size_t whBytes = (size_t)DIM_N * DIM_K * 2;
    _Float16* xh = (_Float16*)(ws + whBytes);                   // [M][K] fp16, 16 MB
    const size_t xhBytes = (size_t)DIM_M * DIM_K * 2;
    _Float16* part = (_Float16*)(ws + whBytes + xhBytes);       // [SPLIT][M][N] fp16, 32 MB
    const size_t partBytes = (size_t)SPLIT * DIM_M * DIM_N * 2;
    uint2* ebuf = (uint2*)(ws + whBytes + xhBytes + partBytes); // nblk*EPB*8 B (<=16 MB)
    const size_t ebufBytes = (size_t)16 << 20;
    unsigned* ofs = (unsigned*)(ws + whBytes + xhBytes + partBytes + ebufBytes); // [NB+1][nblk]

    const int oN4 = DIM_M * DIM_N / 4;
    const int nblk = (nnz + EPB - 1) / EPB;

    hipFuncSetAttribute((const void*)cluster_k,
                        hipFuncAttributeMaxDynamicSharedMemorySize, 71680);
    cluster_k<<<nblk + CVTB, 512, 71680, stream>>>(ind, kv, ebuf, ofs, nnz, nblk,
                                                   (const floatx4*)x, (Half4*)xh);

    hipFuncSetAttribute((const void*)accum_k,
                        hipFuncAttributeMaxDynamicSharedMemorySize, 131072);
    accum_k<<<NB, 1024, 131072, stream>>>(ebuf, ofs, nblk, (Half4*)wh);

    hipFuncSetAttribute((const void*)gemm8_k,
                        hipFuncAttributeMaxDynamicSharedMemorySize, 131072);
    gemm8_k<<<dim3(256), 1024, 131072, stream>>>(xh, wh, part);

    reduce_tanh<<<(oN4 + 255) / 256, 256, 0, stream>>>((const Half4*)part, bias, (floatx4*)out);
}